// Round 11
// baseline (70.786 us; speedup 1.0000x reference)
//
#include <hip/hip_runtime.h>

// HFCFilter: median-pad -> (identity hfc) -> per-(b,c) percentile norm on
// 1/256-quantized copy -> mask.
//
// Key facts exploited:
//  * output = mask ? (x - lo)/(hi - lo) : 0   (padding never reaches output)
//  * percentiles on trunc(res*256)/256 data -> exact via histogram rank scan
//  * (int)(x*1024)>>2 == (int)(x*256) exactly in fp32 -> ONE 1024-bin packed
//    histogram serves median (all pixels, lo16) + quantized percentile
//    (masked-in pixels, hi16). Per-block count 32768 < 2^16: no carry.
//  * x in [0,1) -> quantized mass lives in bins [0,256).
//  * R7 lesson: NO cross-WG sync/fences (non-coherent per-XCD L2s make
//    __threadfence catastrophic). Kernel boundaries publish ws data.
//  * R9 lesson: redundant per-block stats prelude costs more than the 4us
//    stats dispatch. Keep the 3-kernel structure.
//  * R10: ballot bitmask (1 bit/px, 1 MB) replaces norm's 33.6 MB mask read
//    (62.5us). NOW: non-temporal hints on every read-once/write-once stream
//    (mask load, part/bm stores) so x stays L3-resident for norm's re-read;
//    x loads stay cached on purpose.

#define B_       32
#define C_       3
#define BC       (B_ * C_)          // 96 channels
#define HW       (512 * 512)        // 262144 per channel
#define NF4      (HW / 4)           // 65536 float4 per channel
#define NGRP     (NF4 / 64)         // 1024 ballot-groups per channel
#define BINS     1024
#define QB       256                // quantized bins actually occupied
#define PCT_     3.0
#define CHUNKS1  8
#define CHUNKS3  32

typedef float f32x4 __attribute__((ext_vector_type(4)));
typedef unsigned long long u64;

// Pass 1: per-(channel,chunk) private packed histogram -> partial slot.
// c==0 blocks additionally emit the mask bitmask (4 u64 ballots per group).
__global__ __launch_bounds__(256) void hist_kernel(
        const float* __restrict__ x, const float* __restrict__ mask,
        unsigned* __restrict__ part, u64* __restrict__ bm) {
    __shared__ unsigned h[BINS];
    const int ch    = blockIdx.x / CHUNKS1;
    const int chunk = blockIdx.x % CHUNKS1;
    const int b     = ch / C_;
    const int t     = threadIdx.x;
    const int lane  = t & 63;

    for (int i = t; i < BINS; i += 256) h[i] = 0u;
    __syncthreads();

    const f32x4* x4 = (const f32x4*)x    + (size_t)ch * NF4;
    const f32x4* m4 = (const f32x4*)mask + (size_t)b  * NF4;
    const int per_chunk = NF4 / CHUNKS1;   // 8192 float4
    const int base = chunk * per_chunk;
    const bool emit_bm = (ch % C_ == 0);

    for (int i = base + t; i < base + per_chunk; i += 256) {
        f32x4 xv = x4[i];                                   // cached: re-read by norm
        f32x4 mv = __builtin_nontemporal_load(&m4[i]);      // read-once stream
#pragma unroll
        for (int j = 0; j < 4; ++j) {
            int mb = (int)(xv[j] * 1024.0f);
            mb = mb < 0 ? 0 : (mb > BINS - 1 ? BINS - 1 : mb);
            unsigned add = 1u + ((mv[j] > 0.5f) ? 0x10000u : 0u);
            atomicAdd(&h[mb], add);
        }
        // ballot bitmask: 4 u64 per 64-float4 group, lanes 0..3 store
        u64 b0 = __ballot(mv[0] > 0.5f);
        u64 b1 = __ballot(mv[1] > 0.5f);
        u64 b2 = __ballot(mv[2] > 0.5f);
        u64 b3 = __ballot(mv[3] > 0.5f);
        if (emit_bm && lane < 4) {
            u64 v = (lane == 0) ? b0 : (lane == 1) ? b1 : (lane == 2) ? b2 : b3;
            int gi = i >> 6;                     // wave-uniform (base 64-aligned)
            __builtin_nontemporal_store(v,
                &bm[(size_t)b * (NGRP * 4) + (size_t)gi * 4 + lane]);
        }
    }
    __syncthreads();

    unsigned* dst = part + (size_t)blockIdx.x * BINS;   // [ch][chunk][bin]
    for (int i = t; i < BINS; i += 256)
        __builtin_nontemporal_store(h[i], &dst[i]);     // read-once by stats
}

// Pass 2 (parallel): per channel -- sum partials; prefix-scan totals;
// parallel median crossing-search; prefix-scan masked-in q-bins; parallel
// rank search with analytic injection of the masked-out count at bin kb.
__global__ __launch_bounds__(256) void stats_kernel(
        const unsigned* __restrict__ part,
        float* __restrict__ loArr, float* __restrict__ scArr) {
    __shared__ unsigned tot[BINS];
    __shared__ unsigned in1024[BINS];
    __shared__ unsigned ps[256];
    __shared__ unsigned s_mbin[2], s_mcum[2], s_mcnt[2];
    __shared__ unsigned s_qtot;
    __shared__ int      s_kb;
    __shared__ int      s_kv[4];
    const int ch = blockIdx.x;
    const int t  = threadIdx.x;

    const unsigned* p = part + (size_t)ch * CHUNKS1 * BINS;
    for (int bin = t; bin < BINS; bin += 256) {
        unsigned tsum = 0, isum = 0;
#pragma unroll
        for (int c = 0; c < CHUNKS1; ++c) {
            unsigned v = p[(size_t)c * BINS + bin];
            tsum += v & 0xFFFFu;
            isum += v >> 16;
        }
        tot[bin]    = tsum;
        in1024[bin] = isum;
    }
    __syncthreads();

    // scan 1: totals, 4 bins/thread -> median crossing search
    unsigned b0 = tot[4*t], b1 = tot[4*t+1], b2 = tot[4*t+2], b3 = tot[4*t+3];
    unsigned s1 = b0 + b1, s2 = s1 + b2, S = s2 + b3;
    ps[t] = S;
    __syncthreads();
#pragma unroll
    for (int d = 1; d < 256; d <<= 1) {
        unsigned v = (t >= d) ? ps[t - d] : 0u;
        __syncthreads();
        ps[t] += v;
        __syncthreads();
    }
    {
        unsigned excl = ps[t] - S;
        unsigned cp[4] = {excl, excl + b0, excl + s1, excl + s2};
        unsigned ci[4] = {excl + b0, excl + s1, excl + s2, excl + S};
        const unsigned tg0 = HW / 2 - 1, tg1 = HW / 2;
#pragma unroll
        for (int j = 0; j < 4; ++j) {
            if (cp[j] <= tg0 && tg0 < ci[j]) {
                s_mbin[0] = 4*t + j; s_mcum[0] = cp[j]; s_mcnt[0] = ci[j] - cp[j];
            }
            if (cp[j] <= tg1 && tg1 < ci[j]) {
                s_mbin[1] = 4*t + j; s_mcum[1] = cp[j]; s_mcnt[1] = ci[j] - cp[j];
            }
        }
    }
    __syncthreads();

    if (t == 0) {
        const unsigned tgs[2] = {HW / 2 - 1, HW / 2};
        float vals[2];
#pragma unroll
        for (int ti = 0; ti < 2; ++ti) {
            float within = ((float)(tgs[ti] - s_mcum[ti]) + 0.5f) / (float)s_mcnt[ti];
            vals[ti] = ((float)s_mbin[ti] + within) * (1.0f / (float)BINS);
        }
        float med = 0.5f * (vals[0] + vals[1]);
        int kb = (int)((med + 0.2f) * 256.0f);
        s_kb = kb < 0 ? 0 : (kb > QB - 1 ? QB - 1 : kb);
    }
    __syncthreads();

    // scan 2: masked-in counts folded to one q-bin per thread
    unsigned v = in1024[4*t] + in1024[4*t+1] + in1024[4*t+2] + in1024[4*t+3];
    ps[t] = v;
    __syncthreads();
#pragma unroll
    for (int d = 1; d < 256; d <<= 1) {
        unsigned u = (t >= d) ? ps[t - d] : 0u;
        __syncthreads();
        ps[t] += u;
        __syncthreads();
    }
    unsigned Q = ps[t];
    if (t == 255) s_qtot = Q;
    __syncthreads();

    {
        const unsigned mo = (unsigned)HW - s_qtot;
        const int kb = s_kb;
        unsigned cp = (Q - v) + ((t >  kb) ? mo : 0u);
        unsigned ci = Q       + ((t >= kb) ? mo : 0u);
        const double rlo = (PCT_ / 100.0) * (double)(HW - 1);
        const double rhi = ((100.0 - PCT_) / 100.0) * (double)(HW - 1);
        const unsigned ilo = (unsigned)rlo, ihi = (unsigned)rhi;
        const unsigned ranks[4] = {ilo, ilo + 1, ihi, ihi + 1};
#pragma unroll
        for (int ri = 0; ri < 4; ++ri)
            if (cp <= ranks[ri] && ranks[ri] < ci) s_kv[ri] = t;
    }
    __syncthreads();

    if (t == 0) {
        const double rlo = (PCT_ / 100.0) * (double)(HW - 1);
        const double rhi = ((100.0 - PCT_) / 100.0) * (double)(HW - 1);
        const unsigned ilo = (unsigned)rlo, ihi = (unsigned)rhi;
        float fl = (float)(rlo - (double)ilo);
        float fh = (float)(rhi - (double)ihi);
        const float inv256 = 1.0f / 256.0f;
        float v0 = (float)s_kv[0] * inv256, v1 = (float)s_kv[1] * inv256;
        float v2 = (float)s_kv[2] * inv256, v3 = (float)s_kv[3] * inv256;
        float lo = v0 + fl * (v1 - v0);
        float hi = v2 + fh * (v3 - v2);
        loArr[ch] = lo;
        scArr[ch] = 1.0f / (hi - lo);
    }
}

// Pass 3: out = maskbit ? (x - lo) * scale : 0, nontemporal out-stream.
// Mask comes from the 1 MB bitmask (broadcast 32B per 64-lane group).
__global__ __launch_bounds__(256) void norm_kernel(
        const float* __restrict__ x, const u64* __restrict__ bm,
        const float* __restrict__ loArr, const float* __restrict__ scArr,
        float* __restrict__ out) {
    const int ch    = blockIdx.x / CHUNKS3;
    const int chunk = blockIdx.x % CHUNKS3;
    const int b     = ch / C_;
    const int t     = threadIdx.x;
    const int lane  = t & 63;
    const float lo = loArr[ch];
    const float sc = scArr[ch];

    const f32x4* x4 = (const f32x4*)x + (size_t)ch * NF4;
    f32x4*       o4 = (f32x4*)out     + (size_t)ch * NF4;
    const u64*   bmb = bm + (size_t)b * (NGRP * 4);
    const int per_chunk = NF4 / CHUNKS3;   // 2048 float4
    const int base = chunk * per_chunk;

    for (int i = base + t; i < base + per_chunk; i += 256) {
        f32x4 xv = x4[i];                            // hopefully L3-hot from hist
        const u64* g = bmb + (size_t)(i >> 6) * 4;   // wave-uniform addr
        u64 m0 = g[0], m1 = g[1], m2 = g[2], m3 = g[3];
        f32x4 ov;
        ov[0] = ((m0 >> lane) & 1ull) ? (xv[0] - lo) * sc : 0.0f;
        ov[1] = ((m1 >> lane) & 1ull) ? (xv[1] - lo) * sc : 0.0f;
        ov[2] = ((m2 >> lane) & 1ull) ? (xv[2] - lo) * sc : 0.0f;
        ov[3] = ((m3 >> lane) & 1ull) ? (xv[3] - lo) * sc : 0.0f;
        __builtin_nontemporal_store(ov, &o4[i]);
    }
}

extern "C" void kernel_launch(void* const* d_in, const int* in_sizes, int n_in,
                              void* d_out, int out_size, void* d_ws, size_t ws_size,
                              hipStream_t stream) {
    const float* x    = (const float*)d_in[0];
    const float* mask = (const float*)d_in[1];
    float* out = (float*)d_out;

    unsigned* part  = (unsigned*)d_ws;                        // 96*8*1024 u32 = 3.1 MB
    float*    loArr = (float*)(part + BC * CHUNKS1 * BINS);   // 96
    float*    scArr = loArr + BC;                             // 96
    u64*      bm    = (u64*)(scArr + BC);                     // 32*1024*4 u64 = 1 MB

    hist_kernel <<<BC * CHUNKS1, 256, 0, stream>>>(x, mask, part, bm);
    stats_kernel<<<BC,           256, 0, stream>>>(part, loArr, scArr);
    norm_kernel <<<BC * CHUNKS3, 256, 0, stream>>>(x, bm, loArr, scArr, out);
}

// Round 12
// 62.453 us; speedup vs baseline: 1.1334x; 1.1334x over previous
//
#include <hip/hip_runtime.h>

// HFCFilter: median-pad -> (identity hfc) -> per-(b,c) percentile norm on
// 1/256-quantized copy -> mask.
//
// Key facts exploited:
//  * output = mask ? (x - lo)/(hi - lo) : 0   (padding never reaches output)
//  * percentiles on trunc(res*256)/256 data -> exact via histogram rank scan
//  * (int)(x*1024)>>2 == (int)(x*256) exactly in fp32 -> ONE 1024-bin packed
//    histogram serves median (all pixels, lo16) + quantized percentile
//    (masked-in pixels, hi16). Per-block count 32768 < 2^16: no carry.
//  * x in [0,1) -> quantized mass lives in bins [0,256).
//  * R7 lesson: NO cross-WG sync/fences (non-coherent per-XCD L2s make
//    __threadfence catastrophic). Kernel boundaries publish ws data.
//  * R9 lesson: redundant per-block stats prelude costs more than the 4us
//    stats dispatch. Keep the 3-kernel structure.
//  * R10: ballot bitmask (1 bit/px, 1 MB) replaces norm's 33.6 MB mask read.
//  * R11 lesson: nontemporal LOADS (mask) and NT stores on small scratch
//    (part/bm) REGRESS 8us on gfx950 -- nt bypasses L2 and loses coalescing.
//    NT is kept ONLY on the final write-once output stream.

#define B_       32
#define C_       3
#define BC       (B_ * C_)          // 96 channels
#define HW       (512 * 512)        // 262144 per channel
#define NF4      (HW / 4)           // 65536 float4 per channel
#define NGRP     (NF4 / 64)         // 1024 ballot-groups per channel
#define BINS     1024
#define QB       256                // quantized bins actually occupied
#define PCT_     3.0
#define CHUNKS1  8
#define CHUNKS3  32

typedef float f32x4 __attribute__((ext_vector_type(4)));
typedef unsigned long long u64;

// Pass 1: per-(channel,chunk) private packed histogram -> partial slot.
// c==0 blocks additionally emit the mask bitmask (4 u64 ballots per group).
__global__ __launch_bounds__(256) void hist_kernel(
        const float* __restrict__ x, const float* __restrict__ mask,
        unsigned* __restrict__ part, u64* __restrict__ bm) {
    __shared__ unsigned h[BINS];
    const int ch    = blockIdx.x / CHUNKS1;
    const int chunk = blockIdx.x % CHUNKS1;
    const int b     = ch / C_;
    const int t     = threadIdx.x;
    const int lane  = t & 63;

    for (int i = t; i < BINS; i += 256) h[i] = 0u;
    __syncthreads();

    const f32x4* x4 = (const f32x4*)x    + (size_t)ch * NF4;
    const f32x4* m4 = (const f32x4*)mask + (size_t)b  * NF4;
    const int per_chunk = NF4 / CHUNKS1;   // 8192 float4
    const int base = chunk * per_chunk;
    const bool emit_bm = (ch % C_ == 0);

    for (int i = base + t; i < base + per_chunk; i += 256) {
        f32x4 xv = x4[i];
        f32x4 mv = m4[i];
#pragma unroll
        for (int j = 0; j < 4; ++j) {
            int mb = (int)(xv[j] * 1024.0f);
            mb = mb < 0 ? 0 : (mb > BINS - 1 ? BINS - 1 : mb);
            unsigned add = 1u + ((mv[j] > 0.5f) ? 0x10000u : 0u);
            atomicAdd(&h[mb], add);
        }
        // ballot bitmask: 4 u64 per 64-float4 group, lanes 0..3 store
        u64 b0 = __ballot(mv[0] > 0.5f);
        u64 b1 = __ballot(mv[1] > 0.5f);
        u64 b2 = __ballot(mv[2] > 0.5f);
        u64 b3 = __ballot(mv[3] > 0.5f);
        if (emit_bm && lane < 4) {
            u64 v = (lane == 0) ? b0 : (lane == 1) ? b1 : (lane == 2) ? b2 : b3;
            int gi = i >> 6;                     // wave-uniform (base 64-aligned)
            bm[(size_t)b * (NGRP * 4) + (size_t)gi * 4 + lane] = v;
        }
    }
    __syncthreads();

    unsigned* dst = part + (size_t)blockIdx.x * BINS;   // [ch][chunk][bin]
    for (int i = t; i < BINS; i += 256) dst[i] = h[i];
}

// Pass 2 (parallel): per channel -- sum partials; prefix-scan totals;
// parallel median crossing-search; prefix-scan masked-in q-bins; parallel
// rank search with analytic injection of the masked-out count at bin kb.
__global__ __launch_bounds__(256) void stats_kernel(
        const unsigned* __restrict__ part,
        float* __restrict__ loArr, float* __restrict__ scArr) {
    __shared__ unsigned tot[BINS];
    __shared__ unsigned in1024[BINS];
    __shared__ unsigned ps[256];
    __shared__ unsigned s_mbin[2], s_mcum[2], s_mcnt[2];
    __shared__ unsigned s_qtot;
    __shared__ int      s_kb;
    __shared__ int      s_kv[4];
    const int ch = blockIdx.x;
    const int t  = threadIdx.x;

    const unsigned* p = part + (size_t)ch * CHUNKS1 * BINS;
    for (int bin = t; bin < BINS; bin += 256) {
        unsigned tsum = 0, isum = 0;
#pragma unroll
        for (int c = 0; c < CHUNKS1; ++c) {
            unsigned v = p[(size_t)c * BINS + bin];
            tsum += v & 0xFFFFu;
            isum += v >> 16;
        }
        tot[bin]    = tsum;
        in1024[bin] = isum;
    }
    __syncthreads();

    // scan 1: totals, 4 bins/thread -> median crossing search
    unsigned b0 = tot[4*t], b1 = tot[4*t+1], b2 = tot[4*t+2], b3 = tot[4*t+3];
    unsigned s1 = b0 + b1, s2 = s1 + b2, S = s2 + b3;
    ps[t] = S;
    __syncthreads();
#pragma unroll
    for (int d = 1; d < 256; d <<= 1) {
        unsigned v = (t >= d) ? ps[t - d] : 0u;
        __syncthreads();
        ps[t] += v;
        __syncthreads();
    }
    {
        unsigned excl = ps[t] - S;
        unsigned cp[4] = {excl, excl + b0, excl + s1, excl + s2};
        unsigned ci[4] = {excl + b0, excl + s1, excl + s2, excl + S};
        const unsigned tg0 = HW / 2 - 1, tg1 = HW / 2;
#pragma unroll
        for (int j = 0; j < 4; ++j) {
            if (cp[j] <= tg0 && tg0 < ci[j]) {
                s_mbin[0] = 4*t + j; s_mcum[0] = cp[j]; s_mcnt[0] = ci[j] - cp[j];
            }
            if (cp[j] <= tg1 && tg1 < ci[j]) {
                s_mbin[1] = 4*t + j; s_mcum[1] = cp[j]; s_mcnt[1] = ci[j] - cp[j];
            }
        }
    }
    __syncthreads();

    if (t == 0) {
        const unsigned tgs[2] = {HW / 2 - 1, HW / 2};
        float vals[2];
#pragma unroll
        for (int ti = 0; ti < 2; ++ti) {
            float within = ((float)(tgs[ti] - s_mcum[ti]) + 0.5f) / (float)s_mcnt[ti];
            vals[ti] = ((float)s_mbin[ti] + within) * (1.0f / (float)BINS);
        }
        float med = 0.5f * (vals[0] + vals[1]);
        int kb = (int)((med + 0.2f) * 256.0f);
        s_kb = kb < 0 ? 0 : (kb > QB - 1 ? QB - 1 : kb);
    }
    __syncthreads();

    // scan 2: masked-in counts folded to one q-bin per thread
    unsigned v = in1024[4*t] + in1024[4*t+1] + in1024[4*t+2] + in1024[4*t+3];
    ps[t] = v;
    __syncthreads();
#pragma unroll
    for (int d = 1; d < 256; d <<= 1) {
        unsigned u = (t >= d) ? ps[t - d] : 0u;
        __syncthreads();
        ps[t] += u;
        __syncthreads();
    }
    unsigned Q = ps[t];
    if (t == 255) s_qtot = Q;
    __syncthreads();

    {
        const unsigned mo = (unsigned)HW - s_qtot;
        const int kb = s_kb;
        unsigned cp = (Q - v) + ((t >  kb) ? mo : 0u);
        unsigned ci = Q       + ((t >= kb) ? mo : 0u);
        const double rlo = (PCT_ / 100.0) * (double)(HW - 1);
        const double rhi = ((100.0 - PCT_) / 100.0) * (double)(HW - 1);
        const unsigned ilo = (unsigned)rlo, ihi = (unsigned)rhi;
        const unsigned ranks[4] = {ilo, ilo + 1, ihi, ihi + 1};
#pragma unroll
        for (int ri = 0; ri < 4; ++ri)
            if (cp <= ranks[ri] && ranks[ri] < ci) s_kv[ri] = t;
    }
    __syncthreads();

    if (t == 0) {
        const double rlo = (PCT_ / 100.0) * (double)(HW - 1);
        const double rhi = ((100.0 - PCT_) / 100.0) * (double)(HW - 1);
        const unsigned ilo = (unsigned)rlo, ihi = (unsigned)rhi;
        float fl = (float)(rlo - (double)ilo);
        float fh = (float)(rhi - (double)ihi);
        const float inv256 = 1.0f / 256.0f;
        float v0 = (float)s_kv[0] * inv256, v1 = (float)s_kv[1] * inv256;
        float v2 = (float)s_kv[2] * inv256, v3 = (float)s_kv[3] * inv256;
        float lo = v0 + fl * (v1 - v0);
        float hi = v2 + fh * (v3 - v2);
        loArr[ch] = lo;
        scArr[ch] = 1.0f / (hi - lo);
    }
}

// Pass 3: out = maskbit ? (x - lo) * scale : 0, nontemporal out-stream.
// Mask comes from the 1 MB bitmask (broadcast 32B per 64-lane group).
__global__ __launch_bounds__(256) void norm_kernel(
        const float* __restrict__ x, const u64* __restrict__ bm,
        const float* __restrict__ loArr, const float* __restrict__ scArr,
        float* __restrict__ out) {
    const int ch    = blockIdx.x / CHUNKS3;
    const int chunk = blockIdx.x % CHUNKS3;
    const int b     = ch / C_;
    const int t     = threadIdx.x;
    const int lane  = t & 63;
    const float lo = loArr[ch];
    const float sc = scArr[ch];

    const f32x4* x4 = (const f32x4*)x + (size_t)ch * NF4;
    f32x4*       o4 = (f32x4*)out     + (size_t)ch * NF4;
    const u64*   bmb = bm + (size_t)b * (NGRP * 4);
    const int per_chunk = NF4 / CHUNKS3;   // 2048 float4
    const int base = chunk * per_chunk;

    for (int i = base + t; i < base + per_chunk; i += 256) {
        f32x4 xv = x4[i];
        const u64* g = bmb + (size_t)(i >> 6) * 4;   // wave-uniform addr
        u64 m0 = g[0], m1 = g[1], m2 = g[2], m3 = g[3];
        f32x4 ov;
        ov[0] = ((m0 >> lane) & 1ull) ? (xv[0] - lo) * sc : 0.0f;
        ov[1] = ((m1 >> lane) & 1ull) ? (xv[1] - lo) * sc : 0.0f;
        ov[2] = ((m2 >> lane) & 1ull) ? (xv[2] - lo) * sc : 0.0f;
        ov[3] = ((m3 >> lane) & 1ull) ? (xv[3] - lo) * sc : 0.0f;
        __builtin_nontemporal_store(ov, &o4[i]);
    }
}

extern "C" void kernel_launch(void* const* d_in, const int* in_sizes, int n_in,
                              void* d_out, int out_size, void* d_ws, size_t ws_size,
                              hipStream_t stream) {
    const float* x    = (const float*)d_in[0];
    const float* mask = (const float*)d_in[1];
    float* out = (float*)d_out;

    unsigned* part  = (unsigned*)d_ws;                        // 96*8*1024 u32 = 3.1 MB
    float*    loArr = (float*)(part + BC * CHUNKS1 * BINS);   // 96
    float*    scArr = loArr + BC;                             // 96
    u64*      bm    = (u64*)(scArr + BC);                     // 32*1024*4 u64 = 1 MB

    hist_kernel <<<BC * CHUNKS1, 256, 0, stream>>>(x, mask, part, bm);
    stats_kernel<<<BC,           256, 0, stream>>>(part, loArr, scArr);
    norm_kernel <<<BC * CHUNKS3, 256, 0, stream>>>(x, bm, loArr, scArr, out);
}